// Round 7
// baseline (233.584 us; speedup 1.0000x reference)
//
#include <hip/hip_runtime.h>
#include <hip/hip_bf16.h>

// out[256, 100000] = (inputs[256,256] @ features[100000,256]^T) / 0.07
//
// v8 vs v7 (v7 depth-2 prefetch: NULL, 73us @ 2.1 TB/s, FETCH 51MB).
// Record fit: time ~ 60us floor + traffic / (5-10 TB/s). The floor is the
// lockstep-block duty cycle; the ONLY lever that moved BW was v6's second
// independent barrier group per CU (2.1 -> 2.6 TB/s), whose gain was eaten
// by dual-fetch (M-split pair on different XCDs -> different L2s).
// v8: FOUR independent groups per CU, XCD-co-located:
//  - GRID=1024 x 256 thr (4 waves), 4 blocks/CU.
//  - block -> (mh = M-quarter 64 rows, g = n-group) via g=(b&7)|((b>>5)<<3),
//    mh=(b>>3)&3: the 4 blocks sharing n-group g are b,b+8,b+16,b+24 ->
//    SAME XCD (== mod 8, round-robin) and dispatched together -> the 3
//    redundant features reads hit that XCD's L2, not HBM.
//  - BN=32: 100000 = 32*3125 exactly -> all n-bounds checks removed.
//  - regs: pf 32 + afrag 32 + acc 8 + temps ~87 << 128 cap at (256,4).
//    LDS 32x136 dwords = 17408 B x 4 blocks = 69.6 KB.
//  - setprio(1) around MFMA: 4 groups at different phases per CU = the
//    regime where the scheduler has something to arbitrate (T5).
// Kept (proven): stride-136 LDS (0 conflicts), lgkm-only barriers (no
// vmcnt(0) drain), depth-1 reg prefetch (depth-2 null), operand-swapped
// MFMA (4 consecutive n per lane -> float4 stores, exact 100MB WRITE),
// scale folded into A.

typedef __attribute__((ext_vector_type(8))) __bf16 bf16x8;   // 4 VGPRs
typedef __attribute__((ext_vector_type(4))) float  floatx4;  // MFMA acc
typedef __attribute__((ext_vector_type(4))) unsigned int uint4v;

#define NB 100000
#define KD 256
#define BN 32
#define NT32 3125             // NB / BN exact
#define NGROUPS 256
#define GRID 1024             // 4 mh-quarters x 256 n-groups
#define BLK 256               // 4 waves
#define LDS_STRIDE 136        // dwords/row: 128 data + 8 pad (0-conflict)

union FragCast { uint4v u; bf16x8 f; };

__device__ __forceinline__ unsigned pk(float a, float b) {
  // v_cvt_pk_bf16_f32 (RNE)
  __hip_bfloat162 h = __float22bfloat162_rn(float2{a, b});
  union { __hip_bfloat162 h2; unsigned u; } c; c.h2 = h; return c.u;
}

// Workgroup barrier with lgkmcnt(0) only -- no vmcnt(0) drain.
// All cross-wave hazards are LDS (lgkm); global stores have no reader and
// retire lazily; prefetch-load RAW is enforced by the compiler's counted
// vmcnt at the point the pf registers are consumed.
__device__ __forceinline__ void barrier_lgkm() {
  asm volatile("s_waitcnt lgkmcnt(0)" ::: "memory");
  __builtin_amdgcn_s_barrier();
  asm volatile("" ::: "memory");
}

__global__ __launch_bounds__(BLK, 4)
void sct_gemm(const float* __restrict__ inputs,
              const float* __restrict__ features,
              float* __restrict__ out) {
  __shared__ unsigned lds[BN * LDS_STRIDE];   // 17408 B bf16 B-tile

  const int tid  = threadIdx.x;
  const int ws   = tid >> 6;     // wave 0..3 -> m-subtile within quarter
  const int lane = tid & 63;
  const int quad = lane >> 4;
  const int l16  = lane & 15;
  const int q4   = quad * 4;

  const int b  = blockIdx.x;
  const int g  = (b & 7) | ((b >> 5) << 3);   // n-group 0..255
  const int mh = (b >> 3) & 3;                // m-quarter 0..3
  const int ntiles = (NT32 - g + NGROUPS - 1) / NGROUPS;

  // staging: thread covers 128B (32 f32) chunk sk of row srow
  const int srow = tid >> 3, sk = tid & 7;

  // ---- prefetch tile 0 into registers (8 float4 = 32 VGPRs) ----
  float4 pf[8];
  {
    const int n0 = g * BN;
    const float4* p = (const float4*)(features + (size_t)(n0 + srow) * KD + sk * 32);
    #pragma unroll
    for (int j = 0; j < 8; ++j) pf[j] = p[j];
  }

  // ---- A fragments (once per block), scale folded in ----
  const float scale = 1.0f / 0.07f;
  bf16x8 afrag[8];                         // 32 VGPRs
  {
    const float* arow = inputs + (mh * 64 + ws * 16 + l16) * KD + quad * 8;
    #pragma unroll
    for (int t = 0; t < 8; ++t) {
      const float4* p = (const float4*)(arow + t * 32);
      const float4 a0 = p[0], a1 = p[1];
      FragCast fc;
      fc.u.x = pk(a0.x * scale, a0.y * scale);
      fc.u.y = pk(a0.z * scale, a0.w * scale);
      fc.u.z = pk(a1.x * scale, a1.y * scale);
      fc.u.w = pk(a1.z * scale, a1.w * scale);
      afrag[t] = fc.f;
    }
  }

  // lane's output row: m = mh*64 + ws*16 + l16 (operand-swapped D:
  // 4 consecutive n per lane at fixed m)
  float* const orow = out + (size_t)(mh * 64 + ws * 16 + l16) * NB;

  for (int it = 0; it < ntiles; ++it) {
    const int n0 = (g + it * NGROUPS) * BN;

    barrier_lgkm();   // all waves' LDS reads of previous tile retired

    // ---- stage current tile: convert prefetched f32 -> bf16 -> LDS ----
    {
      #pragma unroll
      for (int j = 0; j < 4; ++j) {
        uint4v w;
        w.x = pk(pf[2 * j].x, pf[2 * j].y);
        w.y = pk(pf[2 * j].z, pf[2 * j].w);
        w.z = pk(pf[2 * j + 1].x, pf[2 * j + 1].y);
        w.w = pk(pf[2 * j + 1].z, pf[2 * j + 1].w);
        *(uint4v*)&lds[srow * LDS_STRIDE + (sk * 4 + j) * 4] = w;
      }
    }

    barrier_lgkm();   // staged tile visible to all waves

    // ---- issue prefetch for next tile (consumed next iteration) ----
    if (it + 1 < ntiles) {
      const int nn0 = (g + (it + 1) * NGROUPS) * BN;
      const float4* p = (const float4*)(features + (size_t)(nn0 + srow) * KD + sk * 32);
      #pragma unroll
      for (int j = 0; j < 8; ++j) pf[j] = p[j];
    }

    // ---- MFMA (operand-swapped): 2 n-subtiles, K=256 in 8 steps ----
    floatx4 acc[2];
    #pragma unroll
    for (int nt = 0; nt < 2; ++nt) acc[nt] = floatx4{0.f, 0.f, 0.f, 0.f};

    __builtin_amdgcn_s_setprio(1);
    #pragma unroll
    for (int t = 0; t < 8; ++t) {
      #pragma unroll
      for (int nt = 0; nt < 2; ++nt) {
        FragCast fc;
        fc.u = *(const uint4v*)&lds[(nt * 16 + l16) * LDS_STRIDE + t * 16 + q4];
        acc[nt] = __builtin_amdgcn_mfma_f32_16x16x32_bf16(fc.f, afrag[t], acc[nt], 0, 0, 0);
      }
    }
    __builtin_amdgcn_s_setprio(0);

    // ---- store: one float4 (4 consecutive n) per n-subtile ----
    #pragma unroll
    for (int nt = 0; nt < 2; ++nt) {
      const int n = n0 + nt * 16 + q4;
      *(floatx4*)(orow + n) = acc[nt];   // NB = 32*3125: always in-bounds
    }
  }
}

extern "C" void kernel_launch(void* const* d_in, const int* in_sizes, int n_in,
                              void* d_out, int out_size, void* d_ws, size_t ws_size,
                              hipStream_t stream) {
  const float* inputs   = (const float*)d_in[0];  // [256,256] f32
  // d_in[1] = indexes (unused), d_in[3] = momentum (unused)
  const float* features = (const float*)d_in[2];  // [100000,256] f32
  float* out = (float*)d_out;                     // [256,100000] f32

  sct_gemm<<<GRID, BLK, 0, stream>>>(inputs, features, out);
}

// Round 8
// 198.423 us; speedup vs baseline: 1.1772x; 1.1772x over previous
//
#include <hip/hip_runtime.h>
#include <hip/hip_bf16.h>

// out[256, 100000] = (inputs[256,256] @ features[100000,256]^T) / 0.07
//
// v9 = v6 geometry + v8 co-location mapping (single-variable experiment).
// Evidence: v6 (2 independent 8-wave barrier groups/CU) is the ONLY config
// that moved achieved HBM BW (2.1 -> 2.6 TB/s), but its M-split pair
// (b, b+256) landed on different XCDs -> features fetched twice from HBM
// (FETCH 98MB) -> net wash. v8 proved the fix: mapping the co-readers to
// the SAME XCD (round-robin: equal mod 8) with temporal proximity keeps
// FETCH at 51.9MB -- but v8's 256-thr/BN-32 geometry regressed (barrier
// frequency up 2x, bank conflicts back, waves/group halved).
// v9: keep v6 EXACTLY (512 thr, 8 waves, BN=64, M-half 128 rows,
// stride-136 LDS = 0 conflicts, lgkm-only barriers, depth-1 prefetch,
// setprio around MFMA), change ONLY the block->(g,mh) mapping:
//   g  = (b&7) | ((b>>4)<<3)   (n-group 0..255)
//   mh = (b>>3) & 1            (m-half)
// -> co-readers are blocks b and b+8: same XCD, 8 dispatch slots apart.
// Arithmetic: v6 moved 203MB @ 2.6 TB/s = 78us; v9 moves ~155MB @ >=2.6
// -> <=60us. Decisive counter: FETCH ~52MB (mapping works) vs ~98 (dead).

typedef __attribute__((ext_vector_type(8))) __bf16 bf16x8;   // 4 VGPRs
typedef __attribute__((ext_vector_type(4))) float  floatx4;  // MFMA acc
typedef __attribute__((ext_vector_type(4))) unsigned int uint4v;

#define NB 100000
#define KD 256
#define BN 64
#define NTILES 1563           // ceil(NB / BN)
#define NGROUPS 256
#define GRID 512              // 256 n-groups x 2 m-halves
#define BLK 512               // 8 waves
#define LDS_STRIDE 136        // dwords/row: 128 data + 8 pad (0-conflict)

union FragCast { uint4v u; bf16x8 f; };

__device__ __forceinline__ unsigned pk(float a, float b) {
  // v_cvt_pk_bf16_f32 (RNE)
  __hip_bfloat162 h = __float22bfloat162_rn(float2{a, b});
  union { __hip_bfloat162 h2; unsigned u; } c; c.h2 = h; return c.u;
}

// Workgroup barrier with lgkmcnt(0) only -- no vmcnt(0) drain.
// All cross-wave hazards are LDS (lgkm); global stores have no reader and
// retire lazily; prefetch-load RAW is enforced by the compiler's counted
// vmcnt at the point the pf registers are consumed.
__device__ __forceinline__ void barrier_lgkm() {
  asm volatile("s_waitcnt lgkmcnt(0)" ::: "memory");
  __builtin_amdgcn_s_barrier();
  asm volatile("" ::: "memory");
}

__global__ __launch_bounds__(BLK, 4)
void sct_gemm(const float* __restrict__ inputs,
              const float* __restrict__ features,
              float* __restrict__ out) {
  __shared__ unsigned lds[BN * LDS_STRIDE];   // 34816 B bf16 B-tile

  const int tid  = threadIdx.x;
  const int ws   = tid >> 6;     // wave 0..7 -> m-subtile within half
  const int lane = tid & 63;
  const int quad = lane >> 4;
  const int l16  = lane & 15;
  const int q4   = quad * 4;

  const int b  = blockIdx.x;
  const int g  = (b & 7) | ((b >> 4) << 3);   // n-group 0..255
  const int mh = (b >> 3) & 1;                // m-half: rows [mh*128, +128)
  const int ntiles = (NTILES - g + NGROUPS - 1) / NGROUPS;

  // staging: thread covers 32B chunk sck of rows srow+{0,16,32,48}
  const int srow = tid >> 5, sck = tid & 31;

  // ---- prefetch tile 0 into registers (4 rows x 2 float4 = 32 VGPRs) ----
  float4 pfa[4], pfb[4];
  {
    const int n0 = g * BN;
    #pragma unroll
    for (int j = 0; j < 4; ++j) {
      pfa[j] = pfb[j] = make_float4(0.f, 0.f, 0.f, 0.f);
      const int r = srow + j * 16;
      if (n0 + r < NB) {
        const float4* p = (const float4*)(features + (size_t)(n0 + r) * KD + sck * 8);
        pfa[j] = p[0]; pfb[j] = p[1];
      }
    }
  }

  // ---- A fragments (once per block), scale folded in ----
  const float scale = 1.0f / 0.07f;
  bf16x8 afrag[8];                         // 32 VGPRs
  {
    const float* arow = inputs + (mh * 128 + ws * 16 + l16) * KD + quad * 8;
    #pragma unroll
    for (int t = 0; t < 8; ++t) {
      const float4* p = (const float4*)(arow + t * 32);
      const float4 a0 = p[0], a1 = p[1];
      FragCast fc;
      fc.u.x = pk(a0.x * scale, a0.y * scale);
      fc.u.y = pk(a0.z * scale, a0.w * scale);
      fc.u.z = pk(a1.x * scale, a1.y * scale);
      fc.u.w = pk(a1.z * scale, a1.w * scale);
      afrag[t] = fc.f;
    }
  }

  // lane's output row: m = mh*128 + ws*16 + l16 (operand-swapped D:
  // 4 consecutive n per lane at fixed m)
  float* const orow = out + (size_t)(mh * 128 + ws * 16 + l16) * NB;

  for (int it = 0; it < ntiles; ++it) {
    const int n0 = (g + it * NGROUPS) * BN;

    barrier_lgkm();   // all waves' LDS reads of previous tile retired

    // ---- stage current tile: convert prefetched f32 -> bf16 -> LDS ----
    {
      #pragma unroll
      for (int j = 0; j < 4; ++j) {
        uint4v w;
        w.x = pk(pfa[j].x, pfa[j].y); w.y = pk(pfa[j].z, pfa[j].w);
        w.z = pk(pfb[j].x, pfb[j].y); w.w = pk(pfb[j].z, pfb[j].w);
        *(uint4v*)&lds[(srow + j * 16) * LDS_STRIDE + sck * 4] = w;
      }
    }

    barrier_lgkm();   // staged tile visible to all waves

    // ---- issue prefetch for next tile (consumed next iteration) ----
    if (it + 1 < ntiles) {
      const int nn0 = (g + (it + 1) * NGROUPS) * BN;
      #pragma unroll
      for (int j = 0; j < 4; ++j) {
        pfa[j] = pfb[j] = make_float4(0.f, 0.f, 0.f, 0.f);
        const int r = srow + j * 16;
        if (nn0 + r < NB) {
          const float4* p = (const float4*)(features + (size_t)(nn0 + r) * KD + sck * 8);
          pfa[j] = p[0]; pfb[j] = p[1];
        }
      }
    }

    // ---- MFMA (operand-swapped): 4 n-subtiles, K=256 in 8 steps ----
    floatx4 acc[4];
    #pragma unroll
    for (int nt = 0; nt < 4; ++nt) acc[nt] = floatx4{0.f, 0.f, 0.f, 0.f};

    __builtin_amdgcn_s_setprio(1);
    #pragma unroll
    for (int t = 0; t < 8; ++t) {
      #pragma unroll
      for (int nt = 0; nt < 4; ++nt) {
        FragCast fc;
        fc.u = *(const uint4v*)&lds[(nt * 16 + l16) * LDS_STRIDE + t * 16 + q4];
        acc[nt] = __builtin_amdgcn_mfma_f32_16x16x32_bf16(fc.f, afrag[t], acc[nt], 0, 0, 0);
      }
    }
    __builtin_amdgcn_s_setprio(0);

    // ---- store: one float4 (4 consecutive n) per n-subtile ----
    #pragma unroll
    for (int nt = 0; nt < 4; ++nt) {
      const int n = n0 + nt * 16 + q4;
      if (n < NB)    // NB%16==0 so the float4 is all-in or all-out
        *(floatx4*)(orow + n) = acc[nt];
    }
  }
}

extern "C" void kernel_launch(void* const* d_in, const int* in_sizes, int n_in,
                              void* d_out, int out_size, void* d_ws, size_t ws_size,
                              hipStream_t stream) {
  const float* inputs   = (const float*)d_in[0];  // [256,256] f32
  // d_in[1] = indexes (unused), d_in[3] = momentum (unused)
  const float* features = (const float*)d_in[2];  // [100000,256] f32
  float* out = (float*)d_out;                     // [256,100000] f32

  sct_gemm<<<GRID, BLK, 0, stream>>>(inputs, features, out);
}